// Round 4
// baseline (851.836 us; speedup 1.0000x reference)
//
#include <hip/hip_runtime.h>
#include <hip/hip_bf16.h>
#include <hip/hip_fp16.h>

// MoE top-2 of 8 experts. B=4,T=2048,C=1024,FF=4096 -> N=8192 tokens.
// gate(fp32) -> route (segments padded to BM=256) -> transpose W to [n][k] f16
// -> GEMM1 (x@W1, relu, h f16) -> GEMM2 (h@W2, weighted atomicAdd into out).
// GEMM core: 256x256 tile, BK=32, 4-buffer LDS, counted-vmcnt prefetch DEPTH 2
// (depth 3 races: stage(j+4) hits buffer j&3 while lagging waves read it),
// one s_barrier per K-step, XCD-swizzled nb-fast block order.

#define N_TOK 8192
#define C_DIM 1024
#define F_DIM 4096
#define BM 256
#define M_BLOCKS 72
#define A_ROWS (M_BLOCKS*BM)   // 18432

// workspace layout (bytes); total ~224 MB
#define OFF_TOK  0u            // int[18432]
#define OFF_WGT  73728u        // float[18432]
#define OFF_MBLK 147456u       // int[72] (padded)
#define OFF_TE   148480u       // int2[8192]
#define OFF_TW   214016u       // float2[8192]
#define OFF_XB   279552u       // f16[8192*1024]
#define OFF_WT   17056768u     // f16[8*4096*1024] (W1t then W2t)
#define OFF_H    84165632u     // f16[18432*4096]

typedef __attribute__((ext_vector_type(8))) _Float16 f16x8;
typedef __attribute__((ext_vector_type(4))) float f32x4;
typedef __attribute__((ext_vector_type(8))) unsigned short u16x8;

__device__ __forceinline__ unsigned short f2h_bits(float x) {
    _Float16 h = (_Float16)x;
    return __builtin_bit_cast(unsigned short, h);
}

__device__ __forceinline__ void gload16(const void* g, void* l) {
    __builtin_amdgcn_global_load_lds(
        (const __attribute__((address_space(1))) unsigned int*)g,
        (__attribute__((address_space(3))) unsigned int*)l, 16, 0, 0);
}

// ---------------- gating + x->f16
__global__ __launch_bounds__(256) void gate_kernel(
    const float* __restrict__ x, const float* __restrict__ Wg,
    unsigned short* __restrict__ xb, int2* __restrict__ te, float2* __restrict__ tw)
{
    int w = threadIdx.x >> 6, lam = threadIdx.x & 63;
    int t = blockIdx.x * 4 + w;
    const float* xr = x + (size_t)t * C_DIM;
    unsigned short* xbr = xb + (size_t)t * C_DIM;
    float acc[8] = {0,0,0,0,0,0,0,0};
    for (int it = 0; it < C_DIM/64; ++it) {
        int c = it*64 + lam;
        float v = xr[c];
        xbr[c] = f2h_bits(v);
        const float4* wg = (const float4*)(Wg + c*8);
        float4 a = wg[0], b = wg[1];
        acc[0] += v*a.x; acc[1] += v*a.y; acc[2] += v*a.z; acc[3] += v*a.w;
        acc[4] += v*b.x; acc[5] += v*b.y; acc[6] += v*b.z; acc[7] += v*b.w;
    }
    #pragma unroll
    for (int off = 32; off > 0; off >>= 1)
        #pragma unroll
        for (int e = 0; e < 8; ++e)
            acc[e] += __shfl_xor(acc[e], off);
    if (lam == 0) {
        float m = acc[0];
        #pragma unroll
        for (int e = 1; e < 8; ++e) m = fmaxf(m, acc[e]);
        float ex[8], d = 0.f;
        #pragma unroll
        for (int e = 0; e < 8; ++e) { ex[e] = expf(acc[e] - m); d += ex[e]; }
        int e0 = 0;
        #pragma unroll
        for (int e = 1; e < 8; ++e) if (acc[e] > acc[e0]) e0 = e;
        int e1 = (e0 == 0) ? 1 : 0;
        #pragma unroll
        for (int e = 0; e < 8; ++e) if (e != e0 && acc[e] > acc[e1]) e1 = e;
        float g0 = ex[e0]/d, g1 = ex[e1]/d;
        float s = g0 + g1 + 1e-9f;
        te[t] = make_int2(e0, e1);
        tw[t] = make_float2(g0/s, g1/s);
    }
}

// ---------------- routing: counts -> 256-aligned segments -> scatter token lists
__global__ __launch_bounds__(1024) void route_kernel(
    const int2* __restrict__ te, const float2* __restrict__ tw,
    int* __restrict__ tok, float* __restrict__ wgt, int* __restrict__ mblk)
{
    __shared__ int cnt[8], curs[8], base[8], alen[8];
    int tid = threadIdx.x;
    if (tid < 8) { cnt[tid] = 0; curs[tid] = 0; }
    __syncthreads();
    for (int t = tid; t < N_TOK; t += 1024) {
        int2 ee = te[t];
        atomicAdd(&cnt[ee.x], 1); atomicAdd(&cnt[ee.y], 1);
    }
    __syncthreads();
    if (tid == 0) {
        int b = 0;
        for (int e = 0; e < 8; ++e) {
            base[e] = b;
            int a = ((cnt[e] + BM - 1) / BM) * BM;
            alen[e] = a;
            b += a;
        }
    }
    __syncthreads();
    for (int i = tid; i < A_ROWS; i += 1024) tok[i] = -1;
    for (int mb = tid; mb < M_BLOCKS; mb += 1024) {
        int r = mb * BM, ef = 0;
        for (int e = 0; e < 8; ++e)
            if (r >= base[e] && r < base[e] + alen[e]) ef = e;
        mblk[mb] = ef;
    }
    __syncthreads();
    for (int t = tid; t < N_TOK; t += 1024) {
        int2 ee = te[t]; float2 ww = tw[t];
        int p = atomicAdd(&curs[ee.x], 1);
        tok[base[ee.x] + p] = t; wgt[base[ee.x] + p] = ww.x;
        p = atomicAdd(&curs[ee.y], 1);
        tok[base[ee.y] + p] = t; wgt[base[ee.y] + p] = ww.y;
    }
}

// ---------------- transpose+cvt: [E][R][Cd] fp32 -> [E][Cd][R] f16
__global__ __launch_bounds__(256) void transpose_kernel(
    const float* __restrict__ src, unsigned short* __restrict__ dst, int R, int Cd)
{
    __shared__ float tile[64][65];
    int tcN = Cd >> 6;
    int tilesPerE = (R >> 6) * tcN;
    int bid = blockIdx.x;
    int e = bid / tilesPerE;
    int tt = bid - e * tilesPerE;
    int tr = tt / tcN, tc = tt - tr * tcN;
    int R0 = tr << 6, C0 = tc << 6;
    const float* se = src + (size_t)e * R * Cd;
    unsigned short* de = dst + (size_t)e * R * Cd;
    int tid = threadIdx.x;
    int col4 = (tid & 15) << 2;
    int row0 = tid >> 4;
    #pragma unroll
    for (int j = 0; j < 4; ++j) {
        int row = row0 + j*16;
        float4 v = *(const float4*)(se + (size_t)(R0+row)*Cd + C0 + col4);
        tile[row][col4+0] = v.x; tile[row][col4+1] = v.y;
        tile[row][col4+2] = v.z; tile[row][col4+3] = v.w;
    }
    __syncthreads();
    int oc = tid >> 2;
    int og = tid & 3;
    u16x8 o0, o1;
    #pragma unroll
    for (int i = 0; i < 8; ++i) o0[i] = f2h_bits(tile[og*16 + i][oc]);
    #pragma unroll
    for (int i = 0; i < 8; ++i) o1[i] = f2h_bits(tile[og*16 + 8 + i][oc]);
    unsigned short* dp = de + (size_t)(C0+oc)*R + R0 + og*16;
    *(u16x8*)dp = o0;
    *(u16x8*)(dp + 8) = o1;
}

// ---------------- 256x256 tile, BK=32, 4-buf LDS, counted-vmcnt pipeline depth 2.
// 512 threads = 8 waves (2 wm x 4 wn), per-wave output 128x64.
// LDS tile rows 64B (32 f16), chunk slot = (c + (r>>1)) & 3 (0-conflict, proven R1).
// Race-safety: body j = {STAGE(j+2) -> buf (j+2)&3; vmcnt(8); barrier; read buf j&3}.
// Max skew 1 iter; concurrent writer hits buf (j+3)&3 != j&3. Depth 3 would collide.
template<int K_DIM, int N_COLS, bool GATHER_A, bool RELU_H>
__global__ __launch_bounds__(512, 2) void gemm_kernel(
    const unsigned short* __restrict__ Asrc, const unsigned short* __restrict__ Wt,
    const int* __restrict__ tok, const float* __restrict__ wgt,
    const int* __restrict__ mblk,
    unsigned short* __restrict__ hout, float* __restrict__ out)
{
    constexpr int KT = K_DIM / 32;
    constexpr int NB = N_COLS / 256;
    __shared__ _Float16 As[4][256*32];
    __shared__ _Float16 Bs[4][256*32];

    // bijective XCD swizzle (nwg % 8 == 0 for both grids), nb-fast work order
    constexpr int nwg = NB * M_BLOCKS;
    constexpr int cpx = nwg >> 3;
    int bid = blockIdx.x;
    int wg = (bid & 7) * cpx + (bid >> 3);
    int nb = wg % NB;
    int mb = wg / NB;
    int aBase = mb * BM, nBase = nb * 256;
    if (tok[aBase] < 0) return;          // wholly-padding block (uniform)
    int e = mblk[mb];

    int tid = threadIdx.x, w = tid >> 6, lam = tid & 63;
    int wm = w >> 2, wn = w & 3;

    // staging: per K-tile A=16KB=16 segs(1KB,16 rows), wave w owns segs {2w,2w+1} of A and B
    int rl = lam >> 2;                   // row in seg
    int cg = ((lam & 3) - ((lam >> 3) & 3)) & 3;   // pre-swizzled source chunk
    const char* gA[2]; const char* gB[2];
    #pragma unroll
    for (int i = 0; i < 2; ++i) {
        int s = w*2 + i;
        int tr = s*16 + rl;              // tile row 0..255
        long arow;
        if (GATHER_A) { int tk = tok[aBase + tr]; if (tk < 0) tk = 0; arow = tk; }
        else          { arow = aBase + tr; }
        gA[i] = (const char*)(Asrc + arow*(long)K_DIM) + cg*16;
        gB[i] = (const char*)(Wt + ((long)e*N_COLS + nBase + tr)*(long)K_DIM) + cg*16;
    }

    auto STAGE = [&](int t) {
        int b = t & 3;
        long ko = (long)t * 64;          // 32 f16 per K-step
        gload16(gA[0] + ko, (char*)&As[b][0] + (w*2+0)*1024);
        gload16(gA[1] + ko, (char*)&As[b][0] + (w*2+1)*1024);
        gload16(gB[0] + ko, (char*)&Bs[b][0] + (w*2+0)*1024);
        gload16(gB[1] + ko, (char*)&Bs[b][0] + (w*2+1)*1024);
    };

    // frag read offsets (bytes): slot independent of mi/ni (mi*16>>1 ≡ 0 mod 4)
    int slot = ((lam >> 4) + (((lam & 15)) >> 1)) & 3;
    int rA = wm*128 + (lam & 15);
    int rB = wn*64 + (lam & 15);
    int offA = rA*64 + slot*16;
    int offB = rB*64 + slot*16;

    const f32x4 z = {0.f, 0.f, 0.f, 0.f};
    f32x4 acc[8][4];
    #pragma unroll
    for (int mi = 0; mi < 8; ++mi)
        #pragma unroll
        for (int ni = 0; ni < 4; ++ni) acc[mi][ni] = z;

    STAGE(0); STAGE(1);
    for (int j = 0; j < KT; ++j) {
        if (j + 2 < KT) {
            STAGE(j + 2);
            asm volatile("s_waitcnt vmcnt(8)" ::: "memory");   // stages j+1,j+2 in flight; j drained
        } else if (j + 1 < KT) {
            asm volatile("s_waitcnt vmcnt(4)" ::: "memory");   // stage j+1 in flight; j drained
        } else {
            asm volatile("s_waitcnt vmcnt(0)" ::: "memory");
        }
        __builtin_amdgcn_s_barrier();
        __builtin_amdgcn_sched_barrier(0);
        asm volatile("" ::: "memory");
        const char* Ab = (const char*)&As[j & 3][0];
        const char* Bb = (const char*)&Bs[j & 3][0];
        f16x8 bf[4];
        #pragma unroll
        for (int ni = 0; ni < 4; ++ni)
            bf[ni] = *(const f16x8*)(Bb + offB + ni*1024);
        #pragma unroll
        for (int mi = 0; mi < 8; ++mi) {
            f16x8 af = *(const f16x8*)(Ab + offA + mi*1024);
            #pragma unroll
            for (int ni = 0; ni < 4; ++ni)
                acc[mi][ni] = __builtin_amdgcn_mfma_f32_16x16x32_f16(af, bf[ni], acc[mi][ni], 0, 0, 0);
        }
    }

    // epilogue; C/D: col=lane&15, row=(lane>>4)*4+jj
    int orow = (lam >> 4) * 4;
    int ocol = lam & 15;
    if (RELU_H) {
        #pragma unroll
        for (int mi = 0; mi < 8; ++mi) {
            size_t r0 = (size_t)aBase + wm*128 + mi*16 + orow;
            #pragma unroll
            for (int ni = 0; ni < 4; ++ni) {
                int col = nBase + wn*64 + ni*16 + ocol;
                f32x4 v = acc[mi][ni];
                #pragma unroll
                for (int jj = 0; jj < 4; ++jj)
                    hout[(r0+jj)*(size_t)N_COLS + col] = f2h_bits(fmaxf(v[jj], 0.f));
            }
        }
    } else {
        #pragma unroll
        for (int mi = 0; mi < 8; ++mi) {
            int r0 = aBase + wm*128 + mi*16 + orow;
            #pragma unroll
            for (int jj = 0; jj < 4; ++jj) {
                int tk = tok[r0 + jj];
                if (tk < 0) continue;
                float wv = wgt[r0 + jj];
                float* op = out + (size_t)tk * C_DIM + nBase + wn*64 + ocol;
                #pragma unroll
                for (int ni = 0; ni < 4; ++ni)
                    atomicAdd(op + ni*16, wv * acc[mi][ni][jj]);
            }
        }
    }
}

extern "C" void kernel_launch(void* const* d_in, const int* in_sizes, int n_in,
                              void* d_out, int out_size, void* d_ws, size_t ws_size,
                              hipStream_t stream)
{
    const float* x  = (const float*)d_in[0];
    const float* Wg = (const float*)d_in[1];
    const float* W1 = (const float*)d_in[2];
    const float* W2 = (const float*)d_in[3];
    float* out = (float*)d_out;
    char* ws = (char*)d_ws;

    int*    tok  = (int*)(ws + OFF_TOK);
    float*  wgt  = (float*)(ws + OFF_WGT);
    int*    mblk = (int*)(ws + OFF_MBLK);
    int2*   te   = (int2*)(ws + OFF_TE);
    float2* tw   = (float2*)(ws + OFF_TW);
    unsigned short* xb = (unsigned short*)(ws + OFF_XB);
    unsigned short* wt = (unsigned short*)(ws + OFF_WT);
    unsigned short* h  = (unsigned short*)(ws + OFF_H);

    hipMemsetAsync(d_out, 0, (size_t)out_size * sizeof(float), stream);
    gate_kernel<<<N_TOK/4, 256, 0, stream>>>(x, Wg, xb, te, tw);
    route_kernel<<<1, 1024, 0, stream>>>(te, tw, tok, wgt, mblk);
    transpose_kernel<<<8192, 256, 0, stream>>>(W1, wt, 1024, 4096);
    gemm_kernel<1024, 4096, true,  true ><<<16*M_BLOCKS, 512, 0, stream>>>(xb, wt, tok, wgt, mblk, h, nullptr);
    transpose_kernel<<<8192, 256, 0, stream>>>(W2, wt, 4096, 1024);
    gemm_kernel<4096, 1024, false, false><<<4*M_BLOCKS, 512, 0, stream>>>(h, wt, tok, wgt, mblk, nullptr, out);
}